// Round 8
// baseline (4639.655 us; speedup 1.0000x reference)
//
#include <hip/hip_runtime.h>
#include <math.h>

typedef _Float16 f16;
typedef f16 f16x8 __attribute__((ext_vector_type(8)));
typedef f16 f16x4 __attribute__((ext_vector_type(4)));
typedef float f32x4 __attribute__((ext_vector_type(4)));
typedef unsigned int u32;
typedef unsigned long long u64;

#define TT 64
#define DD 768
#define MR 1024      // B*T = 16*64
#define ALPHAF 0.4f
#define NWG 120      // persistent scan workgroups

__device__ __forceinline__ float geluf(float x){
  return 0.5f*x*(1.0f + erff(x*0.70710678118654752f));
}

// ---- coherent (agent-scope) primitives ----
__device__ __forceinline__ u64 ld_a64(const void* p){
  return __hip_atomic_load((const u64*)p, __ATOMIC_RELAXED, __HIP_MEMORY_SCOPE_AGENT);
}
__device__ __forceinline__ float ld_actf(const float* p){
  union { u32 u; float f; } c;
  c.u = __hip_atomic_load((const u32*)p, __ATOMIC_RELAXED, __HIP_MEMORY_SCOPE_AGENT);
  return c.f;
}

// ---- tagged f16 word: (epoch<<16)|f16bits, atomic 32b ----
__device__ __forceinline__ void st_tagh(u32* p, float v, u32 ep){
  f16 h = (f16)v;
  unsigned short hb = __builtin_bit_cast(unsigned short, h);
  u32 w = (ep<<16) | (u32)hb;
  __hip_atomic_store(p, w, __ATOMIC_RELAXED, __HIP_MEMORY_SCOPE_AGENT);
}
// ---- tagged f32: (epoch<<32)|f32bits, atomic 64b ----
__device__ __forceinline__ void st_tagf(u64* p, float v, u32 ep){
  u32 b = __builtin_bit_cast(u32, v);
  u64 w = ((u64)ep<<32) | (u64)b;
  __hip_atomic_store(p, w, __ATOMIC_RELAXED, __HIP_MEMORY_SCOPE_AGENT);
}
struct T8 { u64 a, b, c, d; };   // 8 tagged words = 8 f16 operand values
__device__ __forceinline__ T8 ld_t8(const u32* p){
  T8 r; r.a = ld_a64(p); r.b = ld_a64(p+2); r.c = ld_a64(p+4); r.d = ld_a64(p+6); return r;
}
__device__ __forceinline__ bool ok_t8(const T8& r, u64 want){
  const u64 M = 0xFFFF0000FFFF0000ull;
  return ((r.a&M)==want) & ((r.b&M)==want) & ((r.c&M)==want) & ((r.d&M)==want);
}
__device__ __forceinline__ f16 lo16(u64 u){ return __builtin_bit_cast(f16,(unsigned short)(u & 0xFFFF)); }
__device__ __forceinline__ f16 hi16(u64 u){ return __builtin_bit_cast(f16,(unsigned short)((u>>32) & 0xFFFF)); }
__device__ __forceinline__ f16x8 val_t8(const T8& r){
  return (f16x8){lo16(r.a),hi16(r.a),lo16(r.b),hi16(r.b),lo16(r.c),hi16(r.c),lo16(r.d),hi16(r.d)};
}
// spin on chunk 0 (cheap), bulk-load rest, verify-retry stragglers
template<int NB>
__device__ __forceinline__ void poll_chunks(const u32* base, u32 ep, T8 (&rg)[NB]){
  const u64 want = ((u64)ep<<16) | ((u64)ep<<48);
  do { rg[0] = ld_t8(base); } while (!ok_t8(rg[0], want));
  #pragma unroll
  for (int b = 1; b < NB; b++) rg[b] = ld_t8(base + b*32);
  while (true){
    bool ok = true;
    #pragma unroll
    for (int b = 1; b < NB; b++)
      if (!ok_t8(rg[b], want)){ rg[b] = ld_t8(base + b*32); ok = false; }
    if (ok) break;
  }
}

// ---------------- embedding ----------------
__global__ __launch_bounds__(256) void k_embed(const int* __restrict__ tok,
    const float* __restrict__ emb, const float* __restrict__ pos, float* __restrict__ x){
  int m = blockIdx.x; int t = m & 63; int id = tok[m];
  const float* e = emb + (size_t)id*DD;
  const float* p = pos + (size_t)t*DD;
  float* xr = x + (size_t)m*DD;
  for (int j = threadIdx.x; j < DD; j += 256) xr[j] = e[j] + p[j];
}

// ---------------- layernorm (+optional l2norm) ----------------
template<bool L2N>
__global__ __launch_bounds__(256) void k_ln(const float* __restrict__ in,
    const float* __restrict__ g, const float* __restrict__ b, float* __restrict__ out){
  __shared__ float red[8];
  int m = blockIdx.x, tid = threadIdx.x, lane = tid & 63, wid = tid >> 6;
  const float* x = in + (size_t)m*DD;
  float v[3]; float s = 0.f, ss = 0.f;
  #pragma unroll
  for (int j = 0; j < 3; j++){ float t0 = x[tid + j*256]; v[j] = t0; s += t0; ss += t0*t0; }
  #pragma unroll
  for (int o = 1; o < 64; o <<= 1){ s += __shfl_xor(s, o); ss += __shfl_xor(ss, o); }
  if (lane == 0){ red[wid] = s; red[4+wid] = ss; }
  __syncthreads();
  s  = red[0]+red[1]+red[2]+red[3];
  ss = red[4]+red[5]+red[6]+red[7];
  float mean = s*(1.f/768.f);
  float var  = ss*(1.f/768.f) - mean*mean;
  float rstd = rsqrtf(var + 1e-5f);
  float y[3];
  #pragma unroll
  for (int j = 0; j < 3; j++){ int n = tid + j*256; y[j] = (v[j]-mean)*rstd*g[n] + b[n]; }
  if (L2N){
    float n2 = y[0]*y[0] + y[1]*y[1] + y[2]*y[2];
    #pragma unroll
    for (int o = 1; o < 64; o <<= 1) n2 += __shfl_xor(n2, o);
    __syncthreads();
    if (lane == 0) red[wid] = n2;
    __syncthreads();
    n2 = red[0]+red[1]+red[2]+red[3];
    float inv = 1.f / fmaxf(sqrtf(n2), 1e-12f);
    y[0] *= inv; y[1] *= inv; y[2] *= inv;
  }
  float* o_ = out + (size_t)m*DD;
  #pragma unroll
  for (int j = 0; j < 3; j++) o_[tid + j*256] = y[j];
}

// ---------------- attention (one WG per (b,h)) ----------------
__global__ __launch_bounds__(256) void k_attn(const float* __restrict__ qkv, float* __restrict__ o){
  __shared__ float kv[64][96];
  __shared__ float sm[64][68];
  int bh = blockIdx.x; int b = bh >> 3, h = bh & 7;
  int tid = threadIdx.x;
  const float* base = qkv + (size_t)b*64*2304 + h*96;
  for (int idx = tid; idx < 64*96; idx += 256){ int i = idx/96, d = idx - i*96;
    kv[i][d] = base[(size_t)i*2304 + 768 + d]; }
  __syncthreads();
  {
    int i = tid >> 2;
    const float* q = base + (size_t)i*2304;
    int j0 = (tid & 3)*16;
    for (int jj = 0; jj < 16; jj++){
      int j = j0 + jj;
      float sv = -1e30f;
      if (j <= i){ float acc = 0.f;
        for (int d = 0; d < 96; d++) acc += q[d]*kv[j][d];
        sv = acc*0.10206207261596576f; }
      sm[i][j] = sv;
    }
  }
  __syncthreads();
  for (int idx = tid; idx < 64*96; idx += 256){ int i = idx/96, d = idx - i*96;
    kv[i][d] = base[(size_t)i*2304 + 1536 + d]; }
  if (tid < 64){
    int i = tid;
    float mx = -1e30f;
    for (int j = 0; j <= i; j++) mx = fmaxf(mx, sm[i][j]);
    float sum = 0.f;
    for (int j = 0; j <= i; j++){ float e = expf(sm[i][j]-mx); sm[i][j] = e; sum += e; }
    float inv = 1.f/sum;
    for (int j = 0; j <= i; j++) sm[i][j] *= inv;
  }
  __syncthreads();
  for (int idx = tid; idx < 64*96; idx += 256){
    int i = idx/96, d = idx - i*96;
    float acc = 0.f;
    for (int j = 0; j <= i; j++) acc += sm[i][j]*kv[j][d];
    o[(size_t)(b*64+i)*768 + h*96 + d] = acc;
  }
}

// -------- generic fp16 MFMA GEMM, XCD-chunked m-inner block order --------
__global__ __launch_bounds__(256) void k_gemm(
    const float* __restrict__ A, int lda,
    const float* __restrict__ Bw, int ldb, int nrb,
    int M, int N, int K, int mblocks,
    const float* __restrict__ bias, const float* __restrict__ res,
    float* __restrict__ outF, f16* __restrict__ outH,
    float scale, int act)
{
  __shared__ f16 As[128][40];
  __shared__ f16 Bs[128][40];
  int tid = threadIdx.x;
  // bijective XCD-chunked decode (m204): consecutive blocks share B-panel & XCD
  int nb = gridDim.x;
  int q = nb >> 3, rm = nb & 7, xcd = blockIdx.x & 7;
  int base0 = (xcd < rm) ? xcd*(q+1) : rm*(q+1) + (xcd - rm)*q;
  int orig = base0 + (blockIdx.x >> 3);
  int m0 = (orig % mblocks)*128, n0 = (orig / mblocks)*128;
  int lane = tid & 63, wid = tid >> 6;
  int wr = (wid >> 1)*64, wc = (wid & 1)*64;
  int l15 = lane & 15, kb = lane >> 4;
  f32x4 acc[4][4];
  #pragma unroll
  for (int i = 0; i < 4; i++)
    #pragma unroll
    for (int j = 0; j < 4; j++){ f32x4 z = {0.f,0.f,0.f,0.f}; acc[i][j] = z; }
  int rA = tid >> 3;          // 0..31
  int k4 = (tid & 7)*4;       // 0..28
  for (int kk = 0; kk < K; kk += 32){
    #pragma unroll
    for (int it = 0; it < 4; ++it){
      int r = it*32 + rA;
      float4 va = *(const float4*)(A + (size_t)(m0+r)*lda + kk + k4);
      *(f16x4*)(&As[r][k4]) = (f16x4){(f16)va.x,(f16)va.y,(f16)va.z,(f16)va.w};
      int rB = n0 + r;
      float4 vb;
      if (rB < nrb) vb = *(const float4*)(Bw + (size_t)rB*ldb + kk + k4);
      else { vb.x = 0.f; vb.y = 0.f; vb.z = 0.f; vb.w = 0.f; }
      *(f16x4*)(&Bs[r][k4]) = (f16x4){(f16)vb.x,(f16)vb.y,(f16)vb.z,(f16)vb.w};
    }
    __syncthreads();
    f16x8 af[4], bfv[4];
    #pragma unroll
    for (int i = 0; i < 4; i++) af[i]  = *(const f16x8*)(&As[wr + i*16 + l15][kb*8]);
    #pragma unroll
    for (int j = 0; j < 4; j++) bfv[j] = *(const f16x8*)(&Bs[wc + j*16 + l15][kb*8]);
    #pragma unroll
    for (int i = 0; i < 4; i++)
      #pragma unroll
      for (int j = 0; j < 4; j++)
        acc[i][j] = __builtin_amdgcn_mfma_f32_16x16x32_f16(af[i], bfv[j], acc[i][j], 0, 0, 0);
    __syncthreads();
  }
  #pragma unroll
  for (int i = 0; i < 4; i++){
    #pragma unroll
    for (int j = 0; j < 4; j++){
      #pragma unroll
      for (int r = 0; r < 4; r++){
        int m = m0 + wr + i*16 + kb*4 + r;
        int n = n0 + wc + j*16 + l15;
        if (n < N){
          float v = acc[i][j][r]*scale;
          if (bias) v += bias[n];
          if (act == 1) v = geluf(v);
          if (res) v += res[(size_t)m*N + n];
          size_t off = (size_t)m*N + n;
          if (outF) outF[off] = v;
          if (outH) outH[off] = (f16)v;
        }
      }
    }
  }
}

// ---------------- transpose / cast helpers ----------------
__global__ __launch_bounds__(256) void k_transpose_f(const float* __restrict__ in, float* __restrict__ out, int R, int C){
  __shared__ float tile[32][33];
  int r0 = blockIdx.y*32, c0 = blockIdx.x*32;
  int tx = threadIdx.x & 31, ty = threadIdx.x >> 5;
  #pragma unroll
  for (int i = 0; i < 32; i += 8) tile[ty+i][tx] = in[(size_t)(r0+ty+i)*C + (c0+tx)];
  __syncthreads();
  #pragma unroll
  for (int i = 0; i < 32; i += 8) out[(size_t)(c0+ty+i)*R + (r0+tx)] = tile[tx][ty+i];
}

__global__ __launch_bounds__(256) void k_transpose_h(const float* __restrict__ in, f16* __restrict__ out, int R, int C){
  __shared__ float tile[32][33];
  int r0 = blockIdx.y*32, c0 = blockIdx.x*32;
  int tx = threadIdx.x & 31, ty = threadIdx.x >> 5;
  #pragma unroll
  for (int i = 0; i < 32; i += 8) tile[ty+i][tx] = in[(size_t)(r0+ty+i)*C + (c0+tx)];
  __syncthreads();
  #pragma unroll
  for (int i = 0; i < 32; i += 8) out[(size_t)(c0+ty+i)*R + (r0+tx)] = (f16)tile[tx][ty+i];
}

__global__ __launch_bounds__(256) void k_cast_h(const float* __restrict__ in, f16* __restrict__ out, int n){
  int i = blockIdx.x*256 + threadIdx.x;
  if (i < n) out[i] = (f16)in[i];
}

__global__ __launch_bounds__(256) void k_bdg(const float* __restrict__ gw, const float* __restrict__ cpb2, float* __restrict__ bdg){
  int g = blockIdx.x*256 + threadIdx.x;
  if (g < 768){
    const float* row = gw + (size_t)g*1536 + 768;
    float s = 0.f;
    for (int j = 0; j < 768; j++) s += cpb2[j]*row[j];
    bdg[g] = s;
  }
}

// ---------------- persistent scan: fp16 weights in LDS, TAGGED DATAFLOW (no barriers) ----------------
// 120 WGs. LDS layout as r7. Tagged buffers:
//   h1T  u32[16][3072], c1T u32[16][768], gcaT u32[16][768]   (f16|tag16)
//   hfT  u32[2][16][768]   2-slot ring over t                 (f16|tag16)
//   cfT, gpreT, tfsT  u64[16][768]                            (f32|tag32)
// Dataflow WAR-safety: every stage consumes the full row-span of its
// producer, so overwrites at t+1 transitively require all t-readers done.

__device__ __forceinline__ void red_store(float* rb, int lane, f32x4 a){
  rb[lane] = a[0]; rb[64+lane] = a[1]; rb[128+lane] = a[2]; rb[192+lane] = a[3];
}
__device__ __forceinline__ f32x4 red_sum4(float rb[4][256], int lane){
  f32x4 s;
  #pragma unroll
  for (int r = 0; r < 4; r++)
    s[r] = rb[0][r*64+lane] + rb[1][r*64+lane] + rb[2][r*64+lane] + rb[3][r*64+lane];
  return s;
}
__device__ __forceinline__ f32x4 red_sum2(float rb[4][256], int lane, int w0, int w1){
  f32x4 s;
  #pragma unroll
  for (int r = 0; r < 4; r++)
    s[r] = rb[w0][r*64+lane] + rb[w1][r*64+lane];
  return s;
}

__global__ __launch_bounds__(256, 1) void k_scan(
  const f16* __restrict__ WAf, const f16* __restrict__ V1tf,
  const f16* __restrict__ Wc1f, const f16* __restrict__ WDf,
  const float* __restrict__ ctxV0b, const float* __restrict__ gctx,
  const float* __restrict__ ctx,
  const float* __restrict__ b1, const float* __restrict__ cpb1,
  const float* __restrict__ cpb2, const float* __restrict__ bdg,
  const float* __restrict__ gateb, const float* __restrict__ outg, const float* __restrict__ outb,
  float* __restrict__ hall,
  u32* __restrict__ h1T, u32* __restrict__ c1T, u32* __restrict__ gcaT,
  u32* __restrict__ hfT, u64* __restrict__ cfT, u64* __restrict__ gpreT,
  u64* __restrict__ tfsT)
{
  __shared__ __align__(16) char smem[147456];
  __shared__ float redbuf[4][256];
  __shared__ float normp[4][16];
  __shared__ float red[8];
  const int tid = threadIdx.x, lane = tid & 63, wid = tid >> 6;
  const int bid = blockIdx.x;
  const int l15 = lane & 15, kb = lane >> 4;

  // ---- stage weights into LDS (once) ----
  {
    const f16* src = WAf + (size_t)bid*32*768;
    for (int c = tid; c < 3072; c += 256){
      int row = c/96, kc = c - row*96;
      int off = (row*1536 + kc*16) ^ ((row&7)<<4);
      *(f16x8*)(smem + off) = *(const f16x8*)(src + (size_t)row*768 + kc*8);
    }
    if (bid < 48){
      const f16* s2 = V1tf + (size_t)bid*16*3072;
      for (int c = tid; c < 6144; c += 256){
        int row = c/384, kc = c - row*384;
        int off = (row*6144 + kc*16) ^ ((row&7)<<4);
        *(f16x8*)(smem + 49152 + off) = *(const f16x8*)(s2 + (size_t)row*3072 + kc*8);
      }
    } else if (bid < 72){
      const f16* s2 = Wc1f + (size_t)(bid-48)*32*768;
      for (int c = tid; c < 3072; c += 256){
        int row = c/96, kc = c - row*96;
        int off = (row*1536 + kc*16) ^ ((row&7)<<4);
        *(f16x8*)(smem + 49152 + off) = *(const f16x8*)(s2 + (size_t)row*768 + kc*8);
      }
    } else {
      const f16* s2 = WDf + (size_t)(bid-72)*32*768;
      for (int c = tid; c < 3072; c += 256){
        int row = c/96, kc = c - row*96;
        int off = (row*1536 + kc*16) ^ ((row&7)<<4);
        *(f16x8*)(smem + 49152 + off) = *(const f16x8*)(s2 + (size_t)row*768 + kc*8);
      }
    }
  }
  __syncthreads();

  for (int t = 0; t < TT; ++t){
    const u32 ep = (u32)(t + 1);
    // ==== stage A (all WGs): 32 output cols of h@WA^T; 2 units x 2 K-half waves
    {
      const int u = wid >> 1, kh = wid & 1;
      const int k0 = kh*384 + kb*8;
      f32x4 a = {0.f,0.f,0.f,0.f};
      if (t > 0){
        const u32* hb = hfT + ((size_t)(((t-1)&1)*16 + l15))*768 + k0;
        T8 rg[12];
        poll_chunks<12>(hb, (u32)t, rg);
        const int row = u*16 + l15, rowoff = row*1536, sw = (row&7)<<4;
        #pragma unroll
        for (int b = 0; b < 12; b++){
          int wb = (rowoff + (k0 + b*32)*2) ^ sw;
          f16x8 vb = *(const f16x8*)(smem + wb);
          a = __builtin_amdgcn_mfma_f32_16x16x32_f16(val_t8(rg[b]), vb, a, 0,0,0);
        }
      }
      red_store(redbuf[wid], lane, a);
    }
    __syncthreads();
    if ((wid & 1) == 0){
      f32x4 s4 = red_sum2(redbuf, lane, wid, wid+1);
      int n = bid*32 + (wid>>1)*16 + l15;
      #pragma unroll
      for (int r = 0; r < 4; r++){
        int m = kb*4 + r;
        if (n < 3072){
          float hv = geluf(s4[r] + ctxV0b[((size_t)m*TT + t)*3072 + n]);
          st_tagh(h1T + (size_t)m*3072 + n, hv, ep);
        } else {
          st_tagf(tfsT + (size_t)m*768 + (n - 3072), s4[r], ep);
        }
      }
    }
    __syncthreads();
    // ==== stage B (bids 0..47): c1 = gelu(h1 @ V1 + b1), K=3072 4-wave split
    if (bid < 48){
      const int k0 = wid*768 + kb*8;
      const u32* hb = h1T + (size_t)l15*3072 + k0;
      T8 rg[24];
      poll_chunks<24>(hb, ep, rg);
      const int rowoff = l15*6144, sw = (l15&7)<<4;
      f32x4 a = {0.f,0.f,0.f,0.f};
      #pragma unroll
      for (int b = 0; b < 24; b++){
        int wb = (rowoff + (k0 + b*32)*2) ^ sw;
        f16x8 vb = *(const f16x8*)(smem + 49152 + wb);
        a = __builtin_amdgcn_mfma_f32_16x16x32_f16(val_t8(rg[b]), vb, a, 0,0,0);
      }
      red_store(redbuf[wid], lane, a);
    }
    __syncthreads();
    if (bid < 48 && wid == 0){
      f32x4 s4 = red_sum4(redbuf, lane);
      int n = bid*16 + l15;
      #pragma unroll
      for (int r = 0; r < 4; r++){
        int m = kb*4 + r;
        st_tagh(c1T + (size_t)m*768 + n, geluf(s4[r] + b1[n]), ep);
      }
    }
    __syncthreads();
    // ==== stage C (bids 48..71): gca = gelu(l2norm(c1)@cp_w1^T + cp_b1); sumsq fused
    if (bid >= 48 && bid < 72){
      const int u = wid >> 1, kh = wid & 1;
      const int k0 = kh*384 + kb*8;
      const u32* cb = c1T + (size_t)l15*768 + k0;
      T8 rg[12];
      poll_chunks<12>(cb, ep, rg);
      const int row = u*16 + l15, rowoff = row*1536, sw = (row&7)<<4;
      f32x4 a = {0.f,0.f,0.f,0.f};
      float sq = 0.f;
      #pragma unroll
      for (int b = 0; b < 12; b++){
        f16x8 va = val_t8(rg[b]);
        int wb = (rowoff + (k0 + b*32)*2) ^ sw;
        f16x8 vb = *(const f16x8*)(smem + 49152 + wb);
        a = __builtin_amdgcn_mfma_f32_16x16x32_f16(va, vb, a, 0,0,0);
        #pragma unroll
        for (int j = 0; j < 8; j++){ float xv = (float)va[j]; sq = fmaf(xv, xv, sq); }
      }
      sq += __shfl_xor(sq,16); sq += __shfl_xor(sq,32);
      if (lane < 16) normp[wid][lane] = sq;
      red_store(redbuf[wid], lane, a);
    }
    __syncthreads();
    if (bid >= 48 && bid < 72 && (wid & 1) == 0){
      f32x4 s4 = red_sum2(redbuf, lane, wid, wid+1);
      int unit = (bid-48)*2 + (wid>>1);
      int n = unit*16 + l15;
      #pragma unroll
      for (int r = 0; r < 4; r++){
        int m = kb*4 + r;
        float nm = normp[wid][m] + normp[wid+1][m];
        float inv = 1.f / fmaxf(sqrtf(nm), 1e-12f);
        st_tagh(gcaT + (size_t)m*768 + n, geluf(s4[r]*inv + cpb1[n]), ep);
      }
    }
    __syncthreads();
    // ==== stage D (bids 72..119): [cf | gate_pre] = gca @ WD^T
    if (bid >= 72){
      const int u = wid >> 1, kh = wid & 1;
      const int k0 = kh*384 + kb*8;
      const u32* gb = gcaT + (size_t)l15*768 + k0;
      T8 rg[12];
      poll_chunks<12>(gb, ep, rg);
      const int row = u*16 + l15, rowoff = row*1536, sw = (row&7)<<4;
      f32x4 a = {0.f,0.f,0.f,0.f};
      #pragma unroll
      for (int b = 0; b < 12; b++){
        int wb = (rowoff + (k0 + b*32)*2) ^ sw;
        f16x8 vb = *(const f16x8*)(smem + 49152 + wb);
        a = __builtin_amdgcn_mfma_f32_16x16x32_f16(val_t8(rg[b]), vb, a, 0,0,0);
      }
      red_store(redbuf[wid], lane, a);
    }
    __syncthreads();
    if (bid >= 72 && (wid & 1) == 0){
      f32x4 s4 = red_sum2(redbuf, lane, wid, wid+1);
      int unit = (bid-72)*2 + (wid>>1);
      int n = unit*16 + l15;            // 0..1535
      #pragma unroll
      for (int r = 0; r < 4; r++){
        int m = kb*4 + r;
        if (n < 768) st_tagf(cfT + (size_t)m*768 + n, s4[r] + cpb2[n], ep);
        else         st_tagf(gpreT + (size_t)m*768 + (n - 768), s4[r] + bdg[n - 768], ep);
      }
    }
    __syncthreads();
    // ==== combine (bids 0..15): gate, h_t = clip(LN(...)), write hf ring
    if (bid < 16){
      int m = bid;
      size_t bidx = ((size_t)m*TT + t)*DD;
      size_t rb = (size_t)m*768;
      u64 c0 = ld_a64(cfT+rb+tid),    c1v = ld_a64(cfT+rb+tid+256),  c2 = ld_a64(cfT+rb+tid+512);
      u64 g0 = ld_a64(gpreT+rb+tid),  g1 = ld_a64(gpreT+rb+tid+256), g2 = ld_a64(gpreT+rb+tid+512);
      u64 f0 = ld_a64(tfsT+rb+tid),   f1 = ld_a64(tfsT+rb+tid+256),  f2 = ld_a64(tfsT+rb+tid+512);
      while (true){
        bool ok = true;
        if ((u32)(c0>>32)!=ep){ c0 = ld_a64(cfT+rb+tid);      ok=false; }
        if ((u32)(c1v>>32)!=ep){ c1v = ld_a64(cfT+rb+tid+256); ok=false; }
        if ((u32)(c2>>32)!=ep){ c2 = ld_a64(cfT+rb+tid+512);  ok=false; }
        if ((u32)(g0>>32)!=ep){ g0 = ld_a64(gpreT+rb+tid);     ok=false; }
        if ((u32)(g1>>32)!=ep){ g1 = ld_a64(gpreT+rb+tid+256); ok=false; }
        if ((u32)(g2>>32)!=ep){ g2 = ld_a64(gpreT+rb+tid+512); ok=false; }
        if ((u32)(f0>>32)!=ep){ f0 = ld_a64(tfsT+rb+tid);      ok=false; }
        if ((u32)(f1>>32)!=ep){ f1 = ld_a64(tfsT+rb+tid+256);  ok=false; }
        if ((u32)(f2>>32)!=ep){ f2 = ld_a64(tfsT+rb+tid+512);  ok=false; }
        if (ok) break;
        __builtin_amdgcn_s_sleep(1);
      }
      float cfv[3] = { __builtin_bit_cast(float,(u32)c0), __builtin_bit_cast(float,(u32)c1v), __builtin_bit_cast(float,(u32)c2) };
      float gpv[3] = { __builtin_bit_cast(float,(u32)g0), __builtin_bit_cast(float,(u32)g1), __builtin_bit_cast(float,(u32)g2) };
      float tfv[3] = { __builtin_bit_cast(float,(u32)f0), __builtin_bit_cast(float,(u32)f1), __builtin_bit_cast(float,(u32)f2) };
      float vals[3]; float s = 0.f, ss = 0.f;
      #pragma unroll
      for (int j = 0; j < 3; j++){
        int n = tid + j*256;
        float gi = gctx[bidx + n] + gpv[j] + gateb[n];
        float gate = 1.f/(1.f + expf(-gi));
        float v = gate*(cfv[j] + tfv[j]) + (1.f - gate)*ctx[bidx + n];
        vals[j] = v; s += v; ss += v*v;
      }
      #pragma unroll
      for (int o = 1; o < 64; o <<= 1){ s += __shfl_xor(s, o); ss += __shfl_xor(ss, o); }
      if (lane == 0){ red[wid] = s; red[4+wid] = ss; }
      __syncthreads();
      s  = red[0]+red[1]+red[2]+red[3];
      ss = red[4]+red[5]+red[6]+red[7];
      float mean = s*(1.f/768.f), var = ss*(1.f/768.f) - mean*mean;
      float rstd = rsqrtf(var + 1e-5f);
      #pragma unroll
      for (int j = 0; j < 3; j++){
        int n = tid + j*256;
        float y = (vals[j]-mean)*rstd*outg[n] + outb[n];
        y = fminf(5.f, fmaxf(-5.f, y));
        hall[bidx + n] = y;
        st_tagh(hfT + ((size_t)((t&1)*16 + m))*768 + n, y, ep);
      }
      __syncthreads();
    }
  }
}

// ---------------- host ----------------
static inline void gemmH(hipStream_t s, const float* A, int lda, const float* Bw, int ldb, int nrb,
                        int M, int N, int K, const float* bias, const float* res,
                        float* outF, f16* outH, float scale, int act){
  int my = M/128, nx = (N + 127)/128;
  k_gemm<<<nx*my, 256, 0, s>>>(A, lda, Bw, ldb, nrb, M, N, K, my, bias, res, outF, outH, scale, act);
}

extern "C" void kernel_launch(void* const* d_in, const int* in_sizes, int n_in,
                              void* d_out, int out_size, void* d_ws, size_t ws_size,
                              hipStream_t stream)
{
  (void)in_sizes; (void)n_in; (void)out_size; (void)ws_size;
  const int*   tok = (const int*)d_in[0];
  const float* emb = (const float*)d_in[1];
  const float* pos = (const float*)d_in[2];
  const float* aiw = (const float*)d_in[3];
  const float* aib = (const float*)d_in[4];
  const float* aow = (const float*)d_in[5];
  const float* aob = (const float*)d_in[6];
  const float* fw1 = (const float*)d_in[7];
  const float* fb1 = (const float*)d_in[8];
  const float* fw2 = (const float*)d_in[9];
  const float* fb2 = (const float*)d_in[10];
  const float* n1g = (const float*)d_in[11];
  const float* n1b = (const float*)d_in[12];
  const float* n2g = (const float*)d_in[13];
  const float* n2b = (const float*)d_in[14];
  const float* eng = (const float*)d_in[15];
  const float* enb = (const float*)d_in[16];
  const float* V0  = (const float*)d_in[17];
  const float* b0  = (const float*)d_in[18];
  const float* V1  = (const float*)d_in[19];
  const float* b1  = (const float*)d_in[20];
  const float* cw1 = (const float*)d_in[21];
  const float* cb1 = (const float*)d_in[22];
  const float* cw2 = (const float*)d_in[23];
  const float* cb2 = (const float*)d_in[24];
  const float* gw  = (const float*)d_in[25];
  const float* gb  = (const float*)d_in[26];
  const float* tw  = (const float*)d_in[27];
  const float* Rm  = (const float*)d_in[28];
  const float* og  = (const float*)d_in[29];
  const float* ob  = (const float*)d_in[30];
  const float* lmw = (const float*)d_in[31];
  float* out = (float*)d_out;

  char* base = (char*)d_ws; size_t off = 0;
  auto alloc = [&](size_t bytes)->void*{
    off = (off + 255) & ~(size_t)255; void* p = base + off; off += bytes; return p; };

  float* x     = (float*)alloc((size_t)MR*DD*4);
  float* xn    = (float*)alloc((size_t)MR*DD*4);
  float* qkv   = (float*)alloc((size_t)MR*2304*4);
  float* o_    = (float*)alloc((size_t)MR*DD*4);
  float* mid   = (float*)alloc((size_t)MR*2048*4);
  float* ctx   = (float*)alloc((size_t)MR*DD*4);
  float* V0t   = (float*)alloc((size_t)3072*768*4);
  float* cw2t  = (float*)alloc((size_t)768*768*4);
  float* ctxV0 = (float*)alloc((size_t)MR*3072*4);
  float* gctx  = (float*)alloc((size_t)MR*DD*4);
  float* hall  = (float*)alloc((size_t)MR*DD*4);
  float* bdg   = (float*)alloc(768*4);
  f16*   WAf   = (f16*)alloc((size_t)3840*768*2);
  f16*   V1tf  = (f16*)alloc((size_t)768*3072*2);
  f16*   Wc1f  = (f16*)alloc((size_t)768*768*2);
  f16*   WDf   = (f16*)alloc((size_t)1536*768*2);
  // tagged dataflow region (contiguous, one memset)
  char*  tagbase = (char*)alloc(0);
  u32*   h1T   = (u32*)alloc((size_t)16*3072*4);
  u32*   c1T   = (u32*)alloc((size_t)16*768*4);
  u32*   gcaT  = (u32*)alloc((size_t)16*768*4);
  u32*   hfT   = (u32*)alloc((size_t)2*16*768*4);
  u64*   cfT   = (u64*)alloc((size_t)16*768*8);
  u64*   gpreT = (u64*)alloc((size_t)16*768*8);
  u64*   tfsT  = (u64*)alloc((size_t)16*768*8);
  size_t tagbytes = (size_t)((char*)alloc(0) - tagbase);

  // ----- encoder -----
  k_embed<<<MR, 256, 0, stream>>>(tok, emb, pos, x);
  for (int l = 0; l < 2; l++){
    k_ln<false><<<MR, 256, 0, stream>>>(x, n1g + l*768, n1b + l*768, xn);
    gemmH(stream, xn, 768, aiw + (size_t)l*2304*768, 768, 2304, MR, 2304, 768,
         aib + l*2304, nullptr, qkv, nullptr, 1.f, 0);
    k_attn<<<128, 256, 0, stream>>>(qkv, o_);
    gemmH(stream, o_, 768, aow + (size_t)l*768*768, 768, 768, MR, 768, 768,
         aob + l*768, x, x, nullptr, 1.f, 0);
    k_ln<false><<<MR, 256, 0, stream>>>(x, n2g + l*768, n2b + l*768, xn);
    gemmH(stream, xn, 768, fw1 + (size_t)l*2048*768, 768, 2048, MR, 2048, 768,
         fb1 + l*2048, nullptr, mid, nullptr, 1.f, 1);
    gemmH(stream, mid, 2048, fw2 + (size_t)l*768*2048, 2048, 768, MR, 768, 2048,
         fb2 + l*768, x, x, nullptr, 1.f, 0);
  }
  k_ln<true><<<MR, 256, 0, stream>>>(x, eng, enb, ctx);

  // ----- precompute -----
  k_transpose_f<<<dim3(3072/32, 768/32), 256, 0, stream>>>(V0, V0t, 768, 3072);
  k_transpose_f<<<dim3(768/32, 768/32), 256, 0, stream>>>(cw2, cw2t, 768, 768);
  k_transpose_h<<<dim3(768/32, 3072/32), 256, 0, stream>>>(V1, V1tf, 3072, 768);
  k_cast_h<<<(768*768 + 255)/256, 256, 0, stream>>>(cw1, Wc1f, 768*768);
  k_cast_h<<<(768*768 + 255)/256, 256, 0, stream>>>(cw2, WDf, 768*768);
  k_bdg<<<3, 256, 0, stream>>>(gw, cb2, bdg);
  // WAf[0:3072][k] = ALPHA*(R@V0)[k][n]
  gemmH(stream, V0t, 768, Rm, 768, 768, 3072, 768, 768, nullptr, nullptr,
       nullptr, WAf, ALPHAF, 0);
  // WAf[3072+j][k] = ALPHA*(R@temp_w^T)[k][j]
  gemmH(stream, tw, 768, Rm, 768, 768, 768, 768, 768, nullptr, nullptr,
       nullptr, WAf + (size_t)3072*768, ALPHAF, 0);
  // ctxV0 = ctx@V0 + b0
  gemmH(stream, ctx, 768, V0t, 768, 3072, MR, 3072, 768, b0, nullptr,
       ctxV0, nullptr, 1.f, 0);
  // gctx = ctx @ gate_w[:, :768]^T
  gemmH(stream, ctx, 768, gw, 1536, 768, MR, 768, 768, nullptr, nullptr,
       gctx, nullptr, 1.f, 0);
  // WDf[768+g][i] = (gate_w[:,768:] @ cp_w2)[g][i]
  gemmH(stream, gw + 768, 1536, cw2t, 768, 768, 768, 768, 768, nullptr, nullptr,
       nullptr, WDf + (size_t)768*768, 1.f, 0);

  // ----- recurrence (tagged dataflow) -----
  hipMemsetAsync(tagbase, 0, tagbytes, stream);
  k_scan<<<NWG, 256, 0, stream>>>(WAf, V1tf, Wc1f, WDf,
      ctxV0, gctx, ctx, b1, cb1, cb2, bdg, gb, og, ob,
      hall, h1T, c1T, gcaT, hfT, cfT, gpreT, tfsT);

  // ----- lm head -----
  gemmH(stream, hall, 768, lmw, 768, 50257, MR, 50257, 768, nullptr, nullptr,
       out, nullptr, 1.f, 0);
}

// Round 9
// 3612.708 us; speedup vs baseline: 1.2843x; 1.2843x over previous
//
#include <hip/hip_runtime.h>
#include <math.h>

typedef _Float16 f16;
typedef f16 f16x8 __attribute__((ext_vector_type(8)));
typedef f16 f16x4 __attribute__((ext_vector_type(4)));
typedef float f32x4 __attribute__((ext_vector_type(4)));
typedef unsigned int u32;
typedef unsigned long long u64;

#define TT 64
#define DD 768
#define MR 1024      // B*T = 16*64
#define ALPHAF 0.4f
#define NWG 120      // persistent scan workgroups

__device__ __forceinline__ float geluf(float x){
  return 0.5f*x*(1.0f + erff(x*0.70710678118654752f));
}

// ---- coherent (agent-scope, LLC) activation accessors ----
__device__ __forceinline__ u64 ld_a64(const void* p){
  return __hip_atomic_load((const u64*)p, __ATOMIC_RELAXED, __HIP_MEMORY_SCOPE_AGENT);
}
__device__ __forceinline__ f16x8 ld_act16h(const f16* p){
  union { u64 u[2]; f16x8 v; } c;
  c.u[0] = ld_a64(p); c.u[1] = ld_a64(p + 4); return c.v;
}
__device__ __forceinline__ float ld_actf(const float* p){
  union { u32 u; float f; } c;
  c.u = __hip_atomic_load((const u32*)p, __ATOMIC_RELAXED, __HIP_MEMORY_SCOPE_AGENT);
  return c.f;
}
__device__ __forceinline__ void st_actf(float* p, float v){
  union { u32 u; float f; } c; c.f = v;
  __hip_atomic_store((u32*)p, c.u, __ATOMIC_RELAXED, __HIP_MEMORY_SCOPE_AGENT);
}
__device__ __forceinline__ void st_acth(f16* p, float v){
  union { unsigned short u; f16 h; } c; c.h = (f16)v;
  __hip_atomic_store((unsigned short*)p, c.u, __ATOMIC_RELAXED, __HIP_MEMORY_SCOPE_AGENT);
}

// ---------------- embedding ----------------
__global__ __launch_bounds__(256) void k_embed(const int* __restrict__ tok,
    const float* __restrict__ emb, const float* __restrict__ pos, float* __restrict__ x){
  int m = blockIdx.x; int t = m & 63; int id = tok[m];
  const float* e = emb + (size_t)id*DD;
  const float* p = pos + (size_t)t*DD;
  float* xr = x + (size_t)m*DD;
  for (int j = threadIdx.x; j < DD; j += 256) xr[j] = e[j] + p[j];
}

// ---------------- layernorm (+optional l2norm, optional [t][b][n] copy) ----------------
template<bool L2N>
__global__ __launch_bounds__(256) void k_ln(const float* __restrict__ in,
    const float* __restrict__ g, const float* __restrict__ b, float* __restrict__ out,
    float* __restrict__ outT){
  __shared__ float red[8];
  int m = blockIdx.x, tid = threadIdx.x, lane = tid & 63, wid = tid >> 6;
  const float* x = in + (size_t)m*DD;
  float v[3]; float s = 0.f, ss = 0.f;
  #pragma unroll
  for (int j = 0; j < 3; j++){ float t0 = x[tid + j*256]; v[j] = t0; s += t0; ss += t0*t0; }
  #pragma unroll
  for (int o = 1; o < 64; o <<= 1){ s += __shfl_xor(s, o); ss += __shfl_xor(ss, o); }
  if (lane == 0){ red[wid] = s; red[4+wid] = ss; }
  __syncthreads();
  s  = red[0]+red[1]+red[2]+red[3];
  ss = red[4]+red[5]+red[6]+red[7];
  float mean = s*(1.f/768.f);
  float var  = ss*(1.f/768.f) - mean*mean;
  float rstd = rsqrtf(var + 1e-5f);
  float y[3];
  #pragma unroll
  for (int j = 0; j < 3; j++){ int n = tid + j*256; y[j] = (v[j]-mean)*rstd*g[n] + b[n]; }
  if (L2N){
    float n2 = y[0]*y[0] + y[1]*y[1] + y[2]*y[2];
    #pragma unroll
    for (int o = 1; o < 64; o <<= 1) n2 += __shfl_xor(n2, o);
    __syncthreads();
    if (lane == 0) red[wid] = n2;
    __syncthreads();
    n2 = red[0]+red[1]+red[2]+red[3];
    float inv = 1.f / fmaxf(sqrtf(n2), 1e-12f);
    y[0] *= inv; y[1] *= inv; y[2] *= inv;
  }
  float* o_ = out + (size_t)m*DD;
  #pragma unroll
  for (int j = 0; j < 3; j++) o_[tid + j*256] = y[j];
  if (outT){
    float* oT = outT + ((size_t)(m & 63)*16 + (m >> 6))*DD;
    #pragma unroll
    for (int j = 0; j < 3; j++) oT[tid + j*256] = y[j];
  }
}

// ---------------- attention (one WG per (b,h)) ----------------
__global__ __launch_bounds__(256) void k_attn(const float* __restrict__ qkv, float* __restrict__ o){
  __shared__ float kv[64][96];
  __shared__ float sm[64][68];
  int bh = blockIdx.x; int b = bh >> 3, h = bh & 7;
  int tid = threadIdx.x;
  const float* base = qkv + (size_t)b*64*2304 + h*96;
  for (int idx = tid; idx < 64*96; idx += 256){ int i = idx/96, d = idx - i*96;
    kv[i][d] = base[(size_t)i*2304 + 768 + d]; }
  __syncthreads();
  {
    int i = tid >> 2;
    const float* q = base + (size_t)i*2304;
    int j0 = (tid & 3)*16;
    for (int jj = 0; jj < 16; jj++){
      int j = j0 + jj;
      float sv = -1e30f;
      if (j <= i){ float acc = 0.f;
        for (int d = 0; d < 96; d++) acc += q[d]*kv[j][d];
        sv = acc*0.10206207261596576f; }
      sm[i][j] = sv;
    }
  }
  __syncthreads();
  for (int idx = tid; idx < 64*96; idx += 256){ int i = idx/96, d = idx - i*96;
    kv[i][d] = base[(size_t)i*2304 + 1536 + d]; }
  if (tid < 64){
    int i = tid;
    float mx = -1e30f;
    for (int j = 0; j <= i; j++) mx = fmaxf(mx, sm[i][j]);
    float sum = 0.f;
    for (int j = 0; j <= i; j++){ float e = expf(sm[i][j]-mx); sm[i][j] = e; sum += e; }
    float inv = 1.f/sum;
    for (int j = 0; j <= i; j++) sm[i][j] *= inv;
  }
  __syncthreads();
  for (int idx = tid; idx < 64*96; idx += 256){
    int i = idx/96, d = idx - i*96;
    float acc = 0.f;
    for (int j = 0; j <= i; j++) acc += sm[i][j]*kv[j][d];
    o[(size_t)(b*64+i)*768 + h*96 + d] = acc;
  }
}

// -------- generic fp16 MFMA GEMM (fp32 in), XCD-chunked m-inner, optional permuted out --------
// operm: 0 -> [m][n]; 1 -> [t][b][n] (m = b*64+t); 2 -> [t][n][b]
__global__ __launch_bounds__(256) void k_gemm(
    const float* __restrict__ A, int lda,
    const float* __restrict__ Bw, int ldb, int nrb,
    int M, int N, int K, int mblocks, int operm,
    const float* __restrict__ bias, const float* __restrict__ res,
    float* __restrict__ outF, f16* __restrict__ outH,
    float scale, int act)
{
  __shared__ f16 As[128][40];
  __shared__ f16 Bs[128][40];
  int tid = threadIdx.x;
  int nb = gridDim.x;
  int q = nb >> 3, rm = nb & 7, xcd = blockIdx.x & 7;
  int base0 = (xcd < rm) ? xcd*(q+1) : rm*(q+1) + (xcd - rm)*q;
  int orig = base0 + (blockIdx.x >> 3);
  int m0 = (orig % mblocks)*128, n0 = (orig / mblocks)*128;
  int lane = tid & 63, wid = tid >> 6;
  int wr = (wid >> 1)*64, wc = (wid & 1)*64;
  int l15 = lane & 15, kb = lane >> 4;
  f32x4 acc[4][4];
  #pragma unroll
  for (int i = 0; i < 4; i++)
    #pragma unroll
    for (int j = 0; j < 4; j++){ f32x4 z = {0.f,0.f,0.f,0.f}; acc[i][j] = z; }
  int rA = tid >> 3;          // 0..31
  int k4 = (tid & 7)*4;       // 0..28
  for (int kk = 0; kk < K; kk += 32){
    #pragma unroll
    for (int it = 0; it < 4; ++it){
      int r = it*32 + rA;
      float4 va = *(const float4*)(A + (size_t)(m0+r)*lda + kk + k4);
      *(f16x4*)(&As[r][k4]) = (f16x4){(f16)va.x,(f16)va.y,(f16)va.z,(f16)va.w};
      int rB = n0 + r;
      float4 vb;
      if (rB < nrb) vb = *(const float4*)(Bw + (size_t)rB*ldb + kk + k4);
      else { vb.x = 0.f; vb.y = 0.f; vb.z = 0.f; vb.w = 0.f; }
      *(f16x4*)(&Bs[r][k4]) = (f16x4){(f16)vb.x,(f16)vb.y,(f16)vb.z,(f16)vb.w};
    }
    __syncthreads();
    f16x8 af[4], bfv[4];
    #pragma unroll
    for (int i = 0; i < 4; i++) af[i]  = *(const f16x8*)(&As[wr + i*16 + l15][kb*8]);
    #pragma unroll
    for (int j = 0; j < 4; j++) bfv[j] = *(const f16x8*)(&Bs[wc + j*16 + l15][kb*8]);
    #pragma unroll
    for (int i = 0; i < 4; i++)
      #pragma unroll
      for (int j = 0; j < 4; j++)
        acc[i][j] = __builtin_amdgcn_mfma_f32_16x16x32_f16(af[i], bfv[j], acc[i][j], 0, 0, 0);
    __syncthreads();
  }
  #pragma unroll
  for (int i = 0; i < 4; i++){
    #pragma unroll
    for (int j = 0; j < 4; j++){
      #pragma unroll
      for (int r = 0; r < 4; r++){
        int m = m0 + wr + i*16 + kb*4 + r;
        int n = n0 + wc + j*16 + l15;
        if (n < N){
          float v = acc[i][j][r]*scale;
          if (bias) v += bias[n];
          if (act == 1) v = geluf(v);
          if (res) v += res[(size_t)m*N + n];
          size_t off;
          if (operm == 0)      off = (size_t)m*N + n;
          else if (operm == 1) off = ((size_t)(m & 63)*16 + (m >> 6))*N + n;
          else                 off = ((size_t)(m & 63)*N + n)*16 + (m >> 6);
          if (outF) outF[off] = v;
          if (outH) outH[off] = (f16)v;
        }
      }
    }
  }
}

// -------- lm-head GEMM: f16 A x f16 B^T -> fp32, XCD-chunked m-inner --------
__global__ __launch_bounds__(256) void k_gemm_hh(
    const f16* __restrict__ A, const f16* __restrict__ Bw,
    int Nout, int K, int mblocks, float* __restrict__ outF)
{
  __shared__ f16 As[128][40];
  __shared__ f16 Bs[128][40];
  int tid = threadIdx.x;
  int nb = gridDim.x;
  int q = nb >> 3, rm = nb & 7, xcd = blockIdx.x & 7;
  int base0 = (xcd < rm) ? xcd*(q+1) : rm*(q+1) + (xcd - rm)*q;
  int orig = base0 + (blockIdx.x >> 3);
  int m0 = (orig % mblocks)*128, n0 = (orig / mblocks)*128;
  int lane = tid & 63, wid = tid >> 6;
  int wr = (wid >> 1)*64, wc = (wid & 1)*64;
  int l15 = lane & 15, kb = lane >> 4;
  f32x4 acc[4][4];
  #pragma unroll
  for (int i = 0; i < 4; i++)
    #pragma unroll
    for (int j = 0; j < 4; j++){ f32x4 z = {0.f,0.f,0.f,0.f}; acc[i][j] = z; }
  int rA = tid >> 2;          // 0..63
  int k8 = (tid & 3)*8;       // 0,8,16,24
  for (int kk = 0; kk < K; kk += 32){
    #pragma unroll
    for (int it = 0; it < 2; ++it){
      int r = it*64 + rA;
      *(f16x8*)(&As[r][k8]) = *(const f16x8*)(A  + (size_t)(m0+r)*K + kk + k8);
      *(f16x8*)(&Bs[r][k8]) = *(const f16x8*)(Bw + (size_t)(n0+r)*K + kk + k8);
    }
    __syncthreads();
    f16x8 af[4], bfv[4];
    #pragma unroll
    for (int i = 0; i < 4; i++) af[i]  = *(const f16x8*)(&As[wr + i*16 + l15][kb*8]);
    #pragma unroll
    for (int j = 0; j < 4; j++) bfv[j] = *(const f16x8*)(&Bs[wc + j*16 + l15][kb*8]);
    #pragma unroll
    for (int i = 0; i < 4; i++)
      #pragma unroll
      for (int j = 0; j < 4; j++)
        acc[i][j] = __builtin_amdgcn_mfma_f32_16x16x32_f16(af[i], bfv[j], acc[i][j], 0, 0, 0);
    __syncthreads();
  }
  #pragma unroll
  for (int i = 0; i < 4; i++){
    #pragma unroll
    for (int j = 0; j < 4; j++){
      #pragma unroll
      for (int r = 0; r < 4; r++){
        int m = m0 + wr + i*16 + kb*4 + r;
        int n = n0 + wc + j*16 + l15;
        if (n < Nout) outF[(size_t)m*Nout + n] = acc[i][j][r];
      }
    }
  }
}

// ---------------- transpose / cast helpers ----------------
__global__ __launch_bounds__(256) void k_transpose_f(const float* __restrict__ in, float* __restrict__ out, int R, int C){
  __shared__ float tile[32][33];
  int r0 = blockIdx.y*32, c0 = blockIdx.x*32;
  int tx = threadIdx.x & 31, ty = threadIdx.x >> 5;
  #pragma unroll
  for (int i = 0; i < 32; i += 8) tile[ty+i][tx] = in[(size_t)(r0+ty+i)*C + (c0+tx)];
  __syncthreads();
  #pragma unroll
  for (int i = 0; i < 32; i += 8) out[(size_t)(c0+ty+i)*R + (r0+tx)] = tile[tx][ty+i];
}

__global__ __launch_bounds__(256) void k_transpose_h(const float* __restrict__ in, f16* __restrict__ out, int R, int C){
  __shared__ float tile[32][33];
  int r0 = blockIdx.y*32, c0 = blockIdx.x*32;
  int tx = threadIdx.x & 31, ty = threadIdx.x >> 5;
  #pragma unroll
  for (int i = 0; i < 32; i += 8) tile[ty+i][tx] = in[(size_t)(r0+ty+i)*C + (c0+tx)];
  __syncthreads();
  #pragma unroll
  for (int i = 0; i < 32; i += 8) out[(size_t)(c0+ty+i)*R + (r0+tx)] = (f16)tile[tx][ty+i];
}

__global__ __launch_bounds__(256) void k_cast_h(const float* __restrict__ in, f16* __restrict__ out, int n){
  int i = blockIdx.x*256 + threadIdx.x;
  if (i < n) out[i] = (f16)in[i];
}

__global__ __launch_bounds__(256) void k_bdg(const float* __restrict__ gw, const float* __restrict__ cpb2, float* __restrict__ bdg){
  int g = blockIdx.x*256 + threadIdx.x;
  if (g < 768){
    const float* row = gw + (size_t)g*1536 + 768;
    float s = 0.f;
    for (int j = 0; j < 768; j++) s += cpb2[j]*row[j];
    bdg[g] = s;
  }
}

__global__ void k_init(int* flags){
  for (int i = threadIdx.x; i < NWG*32; i += 256) flags[i] = 0;
}

// ---------------- persistent scan (fp16 weights pinned in LDS; r7 structure + prefetch/hoist) ----------------
__device__ __forceinline__ void red_store(float* rb, int lane, f32x4 a){
  rb[lane] = a[0]; rb[64+lane] = a[1]; rb[128+lane] = a[2]; rb[192+lane] = a[3];
}
__device__ __forceinline__ f32x4 red_sum4(float rb[4][256], int lane){
  f32x4 s;
  #pragma unroll
  for (int r = 0; r < 4; r++)
    s[r] = rb[0][r*64+lane] + rb[1][r*64+lane] + rb[2][r*64+lane] + rb[3][r*64+lane];
  return s;
}
__device__ __forceinline__ f32x4 red_sum2(float rb[4][256], int lane, int w0, int w1){
  f32x4 s;
  #pragma unroll
  for (int r = 0; r < 4; r++)
    s[r] = rb[w0][r*64+lane] + rb[w1][r*64+lane];
  return s;
}

__device__ __forceinline__ void gbar(int* flags, int ep, int bid){
  asm volatile("s_waitcnt vmcnt(0)" ::: "memory");
  __syncthreads();
  if (threadIdx.x == 0)
    __hip_atomic_store(flags + bid*32, ep, __ATOMIC_RELAXED, __HIP_MEMORY_SCOPE_AGENT);
  int id = threadIdx.x;
  bool active = id < NWG;
  const int* fp = flags + id*32;
  while (true){
    int v = active ? __hip_atomic_load(fp, __ATOMIC_RELAXED, __HIP_MEMORY_SCOPE_AGENT) : ep;
    if (__ballot(v >= ep) == ~0ull) break;
    __builtin_amdgcn_s_sleep(1);
  }
  __syncthreads();
}

__global__ __launch_bounds__(256, 1) void k_scan(
  const f16* __restrict__ WAf, const f16* __restrict__ V1tf,
  const f16* __restrict__ Wc1f, const f16* __restrict__ WDf,
  const float* __restrict__ ctxV0T,   // [t][n3072][b16]
  const float* __restrict__ gctxT,    // [t][b16][768]
  const float* __restrict__ ctxT,     // [t][b16][768]
  const float* __restrict__ b1, const float* __restrict__ cpb1,
  const float* __restrict__ cpb2, const float* __restrict__ bdg,
  const float* __restrict__ gateb, const float* __restrict__ outg, const float* __restrict__ outb,
  f16* __restrict__ hf,
  f16* __restrict__ h1f, f16* __restrict__ c1f, f16* __restrict__ gcaf,
  float* __restrict__ cf, float* __restrict__ gpre,
  float* __restrict__ tfs, int* flags)
{
  __shared__ __align__(16) char smem[147456];
  __shared__ float redbuf[4][256];
  __shared__ float normp[4][16];
  __shared__ float red[8];
  const int tid = threadIdx.x, lane = tid & 63, wid = tid >> 6;
  const int bid = blockIdx.x;
  const int l15 = lane & 15, kb = lane >> 4;

  // ---- stage weights into LDS (once) ----
  {
    const f16* src = WAf + (size_t)bid*32*768;
    for (int c = tid; c < 3072; c += 256){
      int row = c/96, kc = c - row*96;
      int off = (row*1536 + kc*16) ^ ((row&7)<<4);
      *(f16x8*)(smem + off) = *(const f16x8*)(src + (size_t)row*768 + kc*8);
    }
    if (bid < 48){
      const f16* s2 = V1tf + (size_t)bid*16*3072;
      for (int c = tid; c < 6144; c += 256){
        int row = c/384, kc = c - row*384;
        int off = (row*6144 + kc*16) ^ ((row&7)<<4);
        *(f16x8*)(smem + 49152 + off) = *(const f16x8*)(s2 + (size_t)row*3072 + kc*8);
      }
    } else if (bid < 72){
      const f16* s2 = Wc1f + (size_t)(bid-48)*32*768;
      for (int c = tid; c < 3072; c += 256){
        int row = c/96, kc = c - row*96;
        int off = (row*1536 + kc*16) ^ ((row&7)<<4);
        *(f16x8*)(smem + 49152 + off) = *(const f16x8*)(s2 + (size_t)row*768 + kc*8);
      }
    } else {
      const f16* s2 = WDf + (size_t)(bid-72)*32*768;
      for (int c = tid; c < 3072; c += 256){
        int row = c/96, kc = c - row*96;
        int off = (row*1536 + kc*16) ^ ((row&7)<<4);
        *(f16x8*)(smem + 49152 + off) = *(const f16x8*)(s2 + (size_t)row*768 + kc*8);
      }
    }
  }
  __syncthreads();

  // ---- t-invariant hoists ----
  const int n_a = bid*32 + (wid>>1)*16 + l15;
  float b1v = 0.f;
  if (bid < 48) b1v = b1[bid*16 + l15];
  float cpb1v = 0.f;
  if (bid >= 48 && bid < 72) cpb1v = cpb1[((bid-48)*2 + (wid>>1))*16 + l15];
  float dbv = 0.f; int n_d = 0;
  if (bid >= 72){
    n_d = ((bid-72)*2 + (wid>>1))*16 + l15;
    dbv = (n_d < 768) ? cpb2[n_d] : bdg[n_d - 768];
  }
  float gb3[3], og3[3], ob3[3];
  if (bid < 16){
    #pragma unroll
    for (int j = 0; j < 3; j++){
      int n = tid + j*256;
      gb3[j] = gateb[n]; og3[j] = outg[n]; ob3[j] = outb[n];
    }
  }

  int ep = 0;
  for (int t = 0; t < TT; ++t){
    // ---- per-step prefetch: stage-A epilogue slice (coalesced f32x4, [t][n][b]) ----
    f32x4 cv = {0.f,0.f,0.f,0.f};
    if ((wid & 1) == 0 && n_a < 3072)
      cv = *(const f32x4*)(ctxV0T + ((size_t)t*3072 + n_a)*16 + kb*4);

    // ==== stage A (all 120 WGs): 32 output cols of h@WA^T; 2 units x 2 K-half waves
    {
      const int u = wid >> 1, kh = wid & 1;
      const int k0 = kh*384 + kb*8;
      f32x4 a = {0.f,0.f,0.f,0.f};
      if (t > 0){
        const f16* ap = hf + ((size_t)l15*TT + (t-1))*DD + k0;
        const int row = u*16 + l15, rowoff = row*1536, sw = (row&7)<<4;
        #pragma unroll
        for (int b = 0; b < 12; b++){
          int wb = (rowoff + (k0 + b*32)*2) ^ sw;
          f16x8 vb = *(const f16x8*)(smem + wb);
          f16x8 va = ld_act16h(ap + b*32);
          a = __builtin_amdgcn_mfma_f32_16x16x32_f16(va, vb, a, 0,0,0);
        }
      }
      red_store(redbuf[wid], lane, a);
    }
    __syncthreads();
    if ((wid & 1) == 0){
      f32x4 s4 = red_sum2(redbuf, lane, wid, wid+1);
      #pragma unroll
      for (int r = 0; r < 4; r++){
        int m = kb*4 + r;
        if (n_a < 3072){
          float hv = geluf(s4[r] + cv[r]);
          st_acth(h1f + (size_t)m*3072 + n_a, hv);
        } else {
          st_actf(tfs + m*DD + (n_a - 3072), s4[r]);
        }
      }
    }
    gbar(flags, ++ep, bid);
    // ==== stage B (bids 0..47): c1 = gelu(h1 @ V1 + b1), K=3072 4-wave split
    if (bid < 48){
      const int k0 = wid*768 + kb*8;
      const f16* ap = h1f + (size_t)l15*3072 + k0;
      const int rowoff = l15*6144, sw = (l15&7)<<4;
      f32x4 a = {0.f,0.f,0.f,0.f};
      #pragma unroll
      for (int b = 0; b < 24; b++){
        int wb = (rowoff + (k0 + b*32)*2) ^ sw;
        f16x8 vb = *(const f16x8*)(smem + 49152 + wb);
        f16x8 va = ld_act16h(ap + b*32);
        a = __builtin_amdgcn_mfma_f32_16x16x32_f16(va, vb, a, 0,0,0);
      }
      red_store(redbuf[wid], lane, a);
    }
    __syncthreads();
    if (bid < 48 && wid == 0){
      f32x4 s4 = red_sum4(redbuf, lane);
      int n = bid*16 + l15;
      #pragma unroll
      for (int r = 0; r < 4; r++){
        int m = kb*4 + r;
        st_acth(c1f + (size_t)m*DD + n, geluf(s4[r] + b1v));
      }
    }
    gbar(flags, ++ep, bid);
    // ---- combine-slice prefetch (bids 0..15, covers stages C+D) ----
    float gv[3], cxv[3];
    if (bid < 16){
      #pragma unroll
      for (int j = 0; j < 3; j++){
        size_t o = ((size_t)t*16 + bid)*DD + tid + j*256;
        gv[j] = gctxT[o]; cxv[j] = ctxT[o];
      }
    }
    // ==== stage C (bids 48..71): gca = gelu(l2norm(c1)@cp_w1^T + cp_b1); sumsq fused
    if (bid >= 48 && bid < 72){
      const int u = wid >> 1, kh = wid & 1;
      const int k0 = kh*384 + kb*8;
      const f16* ap = c1f + (size_t)l15*DD + k0;
      const int row = u*16 + l15, rowoff = row*1536, sw = (row&7)<<4;
      f32x4 a = {0.f,0.f,0.f,0.f};
      float sq = 0.f;
      #pragma unroll
      for (int b = 0; b < 12; b++){
        int wb = (rowoff + (k0 + b*32)*2) ^ sw;
        f16x8 vb = *(const f16x8*)(smem + 49152 + wb);
        f16x8 va = ld_act16h(ap + b*32);
        a = __builtin_amdgcn_mfma_f32_16x16x32_f16(va, vb, a, 0,0,0);
        #pragma unroll
        for (int j = 0; j < 8; j++){ float xv = (float)va[j]; sq = fmaf(xv, xv, sq); }
      }
      sq += __shfl_xor(sq,16); sq += __shfl_xor(sq,32);
      if (lane < 16) normp[wid][lane] = sq;
      red_store(redbuf[wid], lane, a);
    }
    __syncthreads();
    if (bid >= 48 && bid < 72 && (wid & 1) == 0){
      f32x4 s4 = red_sum2(redbuf, lane, wid, wid+1);
      int n = ((bid-48)*2 + (wid>>1))*16 + l15;
      #pragma unroll
      for (int r = 0; r < 4; r++){
        int m = kb*4 + r;
        float nm = normp[wid][m] + normp[wid+1][m];
        float inv = 1.f / fmaxf(sqrtf(nm), 1e-12f);
        st_acth(gcaf + (size_t)m*DD + n, geluf(s4[r]*inv + cpb1v));
      }
    }
    gbar(flags, ++ep, bid);
    // ==== stage D (bids 72..119): [cf | gate_pre] = gca @ WD^T
    if (bid >= 72){
      const int u = wid >> 1, kh = wid & 1;
      const int k0 = kh*384 + kb*8;
      const f16* ap = gcaf + (size_t)l15*DD + k0;
      const int row = u*16 + l15, rowoff = row*1536, sw = (row&7)<<4;
      f32x4 a = {0.f,0.f,0.f,0.f};
      #pragma unroll
      for (int b = 0; b < 12; b++){
        int wb = (rowoff + (k0 + b*32)*2) ^ sw;
        f16x8 vb = *(const f16x8*)(smem + 49152 + wb);
        f16x8 va = ld_act16h(ap + b*32);
        a = __builtin_amdgcn_mfma_f32_16x16x32_f16(va, vb, a, 0,0,0);
      }
      red_store(redbuf[wid], lane, a);
    }
    __syncthreads();
    if (bid >= 72 && (wid & 1) == 0){
      f32x4 s4 = red_sum2(redbuf, lane, wid, wid+1);
      #pragma unroll
      for (int r = 0; r < 4; r++){
        int m = kb*4 + r;
        if (n_d < 768) st_actf(cf + m*DD + n_d, s4[r] + dbv);
        else           st_actf(gpre + m*DD + (n_d - 768), s4[r] + dbv);
      }
    }
    gbar(flags, ++ep, bid);
    // ==== combine (bids 0..15): gate, h_t = clip(LN(...))
    if (bid < 16){
      int m = bid;
      float vals[3]; float s = 0.f, ss = 0.f;
      #pragma unroll
      for (int j = 0; j < 3; j++){
        int n = tid + j*256;
        float gi = gv[j] + ld_actf(gpre + m*DD + n) + gb3[j];
        float gate = 1.f/(1.f + expf(-gi));
        float v = gate*(ld_actf(cf + m*DD + n) + ld_actf(tfs + m*DD + n)) + (1.f - gate)*cxv[j];
        vals[j] = v; s += v; ss += v*v;
      }
      #pragma unroll
      for (int o = 1; o < 64; o <<= 1){ s += __shfl_xor(s, o); ss += __shfl_xor(ss, o); }
      if (lane == 0){ red[wid] = s; red[4+wid] = ss; }
      __syncthreads();
      s  = red[0]+red[1]+red[2]+red[3];
      ss = red[4]+red[5]+red[6]+red[7];
      float mean = s*(1.f/768.f), var = ss*(1.f/768.f) - mean*mean;
      float rstd = rsqrtf(var + 1e-5f);
      #pragma unroll
      for (int j = 0; j < 3; j++){
        int n = tid + j*256;
        float y = (vals[j]-mean)*rstd*og3[j] + ob3[j];
        y = fminf(5.f, fmaxf(-5.f, y));
        st_acth(hf + ((size_t)m*TT + t)*DD + n, y);
      }
    }
    gbar(flags, ++ep, bid);
  }
}

// ---------------- host ----------------
static inline void gemmH(hipStream_t s, const float* A, int lda, const float* Bw, int ldb, int nrb,
                        int M, int N, int K, int operm, const float* bias, const float* res,
                        float* outF, f16* outH, float scale, int act){
  int my = M/128, nx = (N + 127)/128;
  k_gemm<<<nx*my, 256, 0, s>>>(A, lda, Bw, ldb, nrb, M, N, K, my, operm, bias, res, outF, outH, scale, act);
}

extern "C" void kernel_launch(void* const* d_in, const int* in_sizes, int n_in,
                              void* d_out, int out_size, void* d_ws, size_t ws_size,
                              hipStream_t stream)
{
  (void)in_sizes; (void)n_in; (void)out_size; (void)ws_size;
  const int*   tok = (const int*)d_in[0];
  const float* emb = (const float*)d_in[1];
  const float* pos = (const float*)d_in[2];
  const float* aiw = (const float*)d_in[3];
  const float* aib = (const float*)d_in[4];
  const float* aow = (const float*)d_in[5];
  const float* aob = (const float*)d_in[6];
  const float* fw1 = (const float*)d_in[7];
  const float* fb1 = (const float*)d_in[8];
  const float* fw2 = (const float*)d_in[9];
  const float* fb2 = (const float*)d_in[10];
  const float* n1g = (const float*)d_in[11];
  const float* n1b = (const float*)d_in[12];
  const float* n2g = (const float*)d_in[13];
  const float* n2b = (const float*)d_in[14];
  const float* eng = (const float*)d_in[15];
  const float* enb = (const float*)d_in[16];
  const float* V0  = (const float*)d_in[17];
  const float* b0  = (const float*)d_in[18];
  const float* V1  = (const float*)d_in[19];
  const float* b1  = (const float*)d_in[20];
  const float* cw1 = (const float*)d_in[21];
  const float* cb1 = (const float*)d_in[22];
  const float* cw2 = (const float*)d_in[23];
  const float* cb2 = (const float*)d_in[24];
  const float* gw  = (const float*)d_in[25];
  const float* gb  = (const float*)d_in[26];
  const float* tw  = (const float*)d_in[27];
  const float* Rm  = (const float*)d_in[28];
  const float* og  = (const float*)d_in[29];
  const float* ob  = (const float*)d_in[30];
  const float* lmw = (const float*)d_in[31];
  float* out = (float*)d_out;

  char* base = (char*)d_ws; size_t off = 0;
  auto alloc = [&](size_t bytes)->void*{
    off = (off + 255) & ~(size_t)255; void* p = base + off; off += bytes; return p; };

  float* x     = (float*)alloc((size_t)MR*DD*4);
  float* xn    = (float*)alloc((size_t)MR*DD*4);
  float* qkv   = (float*)alloc((size_t)MR*2304*4);
  float* o_    = (float*)alloc((size_t)MR*DD*4);
  float* mid   = (float*)alloc((size_t)MR*2048*4);
  float* ctx   = (float*)alloc((size_t)MR*DD*4);
  float* ctxT  = (float*)alloc((size_t)MR*DD*4);
  float* V0t   = (float*)alloc((size_t)3072*768*4);
  float* cw2t  = (float*)alloc((size_t)768*768*4);
  float* ctxV0T= (float*)alloc((size_t)MR*3072*4);
  float* gctxT = (float*)alloc((size_t)MR*DD*4);
  float* bdg   = (float*)alloc(768*4);
  f16*   WAf   = (f16*)alloc((size_t)3840*768*2);
  f16*   V1tf  = (f16*)alloc((size_t)768*3072*2);
  f16*   Wc1f  = (f16*)alloc((size_t)768*768*2);
  f16*   WDf   = (f16*)alloc((size_t)1536*768*2);
  f16*   lmw16 = (f16*)alloc((size_t)50304*768*2);
  f16*   hf    = (f16*)alloc((size_t)MR*DD*2);
  f16*   h1f   = (f16*)alloc((size_t)16*3072*2);
  f16*   c1f   = (f16*)alloc((size_t)16*768*2);
  f16*   gcaf  = (f16*)alloc((size_t)16*768*2);
  float* cf    = (float*)alloc((size_t)16*768*4);
  float* gpre  = (float*)alloc((size_t)16*768*4);
  float* tfs   = (float*)alloc((size_t)16*768*4);
  int*   flags = (int*)alloc((size_t)NWG*32*4);

  // ----- encoder -----
  k_embed<<<MR, 256, 0, stream>>>(tok, emb, pos, x);
  for (int l = 0; l < 2; l++){
    k_ln<false><<<MR, 256, 0, stream>>>(x, n1g + l*768, n1b + l*768, xn, nullptr);
    gemmH(stream, xn, 768, aiw + (size_t)l*2304*768, 768, 2304, MR, 2304, 768, 0,
         aib + l*2304, nullptr, qkv, nullptr, 1.f, 0);
    k_attn<<<128, 256, 0, stream>>>(qkv, o_);
    gemmH(stream, o_, 768, aow + (size_t)l*768*768, 768, 768, MR, 768, 768, 0,
         aob + l*768, x, x, nullptr, 1.f, 0);
    k_ln<false><<<MR, 256, 0, stream>>>(x, n2g + l*768, n2b + l*768, xn, nullptr);
    gemmH(stream, xn, 768, fw1 + (size_t)l*2048*768, 768, 2048, MR, 2048, 768, 0,
         fb1 + l*2048, nullptr, mid, nullptr, 1.f, 1);
    gemmH(stream, mid, 2048, fw2 + (size_t)l*768*2048, 2048, 768, MR, 768, 2048, 0,
         fb2 + l*768, x, x, nullptr, 1.f, 0);
  }
  k_ln<true><<<MR, 256, 0, stream>>>(x, eng, enb, ctx, ctxT);

  // ----- precompute -----
  k_transpose_f<<<dim3(3072/32, 768/32), 256, 0, stream>>>(V0, V0t, 768, 3072);
  k_transpose_f<<<dim3(768/32, 768/32), 256, 0, stream>>>(cw2, cw2t, 768, 768);
  k_transpose_h<<<dim3(768/32, 3072/32), 256, 0, stream>>>(V1, V1tf, 3072, 768);
  k_cast_h<<<(768*768 + 255)/256, 256, 0, stream>>>(cw1, Wc1f, 768*768);
  k_cast_h<<<(768*768 + 255)/256, 256, 0, stream>>>(cw2, WDf, 768*768);
  k_cast_h<<<(50257*768 + 255)/256, 256, 0, stream>>>(lmw, lmw16, 50257*768);
  hipMemsetAsync(lmw16 + (size_t)50257*768, 0, (size_t)(50304-50257)*768*2, stream);
  k_bdg<<<3, 256, 0, stream>>>(gw, cb2, bdg);
  gemmH(stream, V0t, 768, Rm, 768, 768, 3072, 768, 768, 0, nullptr, nullptr,
       nullptr, WAf, ALPHAF, 0);
  gemmH(stream, tw, 768, Rm, 768, 768, 768, 768, 768, 0, nullptr, nullptr,
       nullptr, WAf + (size_t)3072*768, ALPHAF, 0);
  // ctxV0T[t][n][b] = (ctx@V0 + b0)
  gemmH(stream, ctx, 768, V0t, 768, 3072, MR, 3072, 768, 2, b0, nullptr,
       ctxV0T, nullptr, 1.f, 0);
  // gctxT[t][b][n] = ctx @ gate_w[:, :768]^T
  gemmH(stream, ctx, 768, gw, 1536, 768, MR, 768, 768, 1, nullptr, nullptr,
       gctxT, nullptr, 1.f, 0);
  gemmH(stream, gw + 768, 1536, cw2t, 768, 768, 768, 768, 768, 0, nullptr, nullptr,
       nullptr, WDf + (size_t)768*768, 1.f, 0);

  // ----- recurrence -----
  k_init<<<1, 256, 0, stream>>>(flags);
  k_scan<<<NWG, 256, 0, stream>>>(WAf, V1tf, Wc1f, WDf,
      ctxV0T, gctxT, ctxT, b1, cb1, cb2, bdg, gb, og, ob,
      hf, h1f, c1f, gcaf, cf, gpre, tfs, flags);

  // ----- lm head (f16 x f16) -----
  k_gemm_hh<<<(50304/128)*(MR/128), 256, 0, stream>>>(hf, lmw16, 50257, 768, MR/128, out);
}